// Round 8
// baseline (175.667 us; speedup 1.0000x reference)
//
#include <hip/hip_runtime.h>

// Luong attention, flash-style, f16 MFMA, 1-wave/SIMD ILP structure.
// enc [B,Te,D] f32, dec [B,Td,D] f32 -> out [B,Td,2D] f32 (concat(dec, context))
// Prepass: enc -> encK f16 (row-major, 16B-chunk swizzle x^=e&7 within 64d group)
//          enc -> encVt f16 [b][e/32][d][4 chunks]{e=4g..4g+3, e=16+4g..+3}, chunk pos ^=(d>>1)&3
// Main: 256 thr = 2 e-groups x 2 t-waves(32 q-rows each). KBLK=32.
//   K 3-deep LDS, V 2-deep LDS (160 KiB). Per iter: [QK(it+1) || SM(it)] -> PV(it)
//   -> vmcnt(0)+lgkm(0) -> barrier -> stage K(it+3),V(it+2). One barrier/iter.

#define B_   8
#define TE   2048
#define TD   2048
#define D_   256
#define NIT  32   // (TE/2)/32 k-tiles per e-group

typedef _Float16 f16x8 __attribute__((ext_vector_type(8)));
typedef _Float16 f16x4 __attribute__((ext_vector_type(4)));
typedef float f32x4 __attribute__((ext_vector_type(4)));

__device__ __forceinline__ unsigned pk2(float a, float b) {
  unsigned short ua = __builtin_bit_cast(unsigned short, (_Float16)a);
  unsigned short ub = __builtin_bit_cast(unsigned short, (_Float16)b);
  return (unsigned)ua | ((unsigned)ub << 16);
}

#define GLOAD16(gsrc, ldst)                                                  \
  __builtin_amdgcn_global_load_lds(                                          \
      (const __attribute__((address_space(1))) unsigned int*)(const void*)(gsrc), \
      (__attribute__((address_space(3))) unsigned int*)(void*)(ldst), 16, 0, 0)

// ---- fused prepass: one 64e x 64d f32 tile -> encK chunk + encVt chunk ----
__global__ __launch_bounds__(256) void prep_fused(const float* __restrict__ enc,
                                                  _Float16* __restrict__ encK,
                                                  _Float16* __restrict__ encVt) {
  __shared__ float tile[64][65];
  int bid = blockIdx.x;                 // 8 b * 32 et * 4 dt = 1024
  int b = bid >> 7, r = bid & 127;
  int et = r >> 2, dt = r & 3;
  int e0 = et * 64, d0 = dt * 64;
  int tx = threadIdx.x & 63, ty = threadIdx.x >> 6;
  const float* src = enc + ((size_t)b * TE + e0) * D_ + d0;
#pragma unroll
  for (int i = 0; i < 16; ++i)
    tile[i * 4 + ty][tx] = src[(size_t)(i * 4 + ty) * D_ + tx];
  __syncthreads();

  // encK: chunk xl of row e holds source chunk xl^(e&7) (within this 64d group)
  _Float16* kout = encK + ((size_t)b * TE + e0) * D_ + d0;
#pragma unroll
  for (int i = 0; i < 2; ++i) {
    int ci = i * 256 + threadIdx.x;     // 0..511
    int e = ci >> 3, xl = ci & 7;
    int xs = xl ^ (e & 7);
    const float* s8 = &tile[e][xs * 8];
    f16x8 h;
#pragma unroll
    for (int j = 0; j < 8; ++j) h[j] = (_Float16)s8[j];
    *(f16x8*)(kout + (size_t)e * D_ + xl * 8) = h;
  }
  // encVt: per (ct, d): 4 chunks of 16B; chunk at pos gpos (gs = gpos^((d>>1)&3))
  // holds {e=ct*32+4gs..+3, e=ct*32+16+4gs..+3}
#pragma unroll
  for (int i = 0; i < 2; ++i) {
    int u = i * 256 + threadIdx.x;      // 0..511
    int gpos = u & 3, d_loc = (u >> 2) & 63, ctl = u >> 8;
    int gs = gpos ^ ((d_loc >> 1) & 3);
    int eb = ctl * 32 + 4 * gs;
    f16x8 h;
#pragma unroll
    for (int j = 0; j < 4; ++j) h[j] = (_Float16)tile[eb + j][d_loc];
#pragma unroll
    for (int j = 0; j < 4; ++j) h[4 + j] = (_Float16)tile[eb + 16 + j][d_loc];
    size_t o = (((size_t)b * 64 + et * 2 + ctl) * 256 + d0 + d_loc) * 32 + gpos * 8;
    *(f16x8*)(encVt + o) = h;
  }
}

__global__ __launch_bounds__(256, 1) void luong_main(
    const _Float16* __restrict__ encK,   // [B][TE][256] swizzled
    const _Float16* __restrict__ encVt,  // [B][64][256][32] tiled/interleaved
    const float* __restrict__ dec,
    float* __restrict__ out) {
  extern __shared__ char lds[];
  const int tid = threadIdx.x;
  const int lane = tid & 63, wave = tid >> 6;     // 4 waves
  const int wr = wave >> 1, tw = wave & 1;        // e-group, t-wave
  const int g = lane >> 4, c = lane & 15;

  int bidl = (blockIdx.x & 7) * 32 + (blockIdx.x >> 3);  // XCD-contiguous batches
  const int b = bidl >> 5;
  const int q0 = (bidl & 31) * 64;
  const int tbase = q0 + tw * 32;                 // this wave's 32 q-cols

  const float* decB = dec + (size_t)b * TD * D_;
  float* outB = out + (size_t)b * TD * (2 * D_);

  const _Float16* kbase = encK + ((size_t)b * TE + wr * 1024) * D_;
  const _Float16* vbase = encVt + ((size_t)b * 64 + wr * 32) * 8192;

  char* grpK = lds + (size_t)wr * 81920;          // 3 x 16 KiB
  char* grpV = grpK + 49152;                      // 2 x 16 KiB

  auto KSTAGE = [&](int slot, int it) {
    char* Kd = grpK + slot * 16384 + tw * 8192;
    const _Float16* ks = kbase + (size_t)it * 8192 + tw * 4096;
#pragma unroll
    for (int q = 0; q < 8; ++q)
      GLOAD16(ks + q * 512 + lane * 8, Kd + q * 1024);
  };
  auto VSTAGE = [&](int slot, int it) {
    char* Vd = grpV + slot * 16384 + tw * 8192;
    const _Float16* vs = vbase + (size_t)it * 8192 + tw * 4096;
#pragma unroll
    for (int q = 0; q < 8; ++q)
      GLOAD16(vs + q * 512 + lane * 8, Vd + q * 1024);
  };

  // ---- prologue stages: K0,K1,K2, V0,V1 ----
  KSTAGE(0, 0); VSTAGE(0, 0); KSTAGE(1, 1); VSTAGE(1, 1); KSTAGE(2, 2);

  // dec -> out[:, :256] copy (overlaps staging flight)
#pragma unroll
  for (int i = 0; i < 16; ++i) {
    int ci = tid + 256 * i;
    int rr = ci >> 6, d4 = (ci & 63) << 2;
    *(float4*)(outB + (size_t)(q0 + rr) * 512 + d4) =
        *(const float4*)(decB + (size_t)(q0 + rr) * 256 + d4);
  }

  // ---- Q fragments f16 hi/lo, 2 t-tiles ----
  f16x8 qh[2][8], ql[2][8];
#pragma unroll
  for (int tt = 0; tt < 2; ++tt) {
    const float* qrow = decB + (size_t)(tbase + tt * 16 + c) * D_;
#pragma unroll
    for (int dc = 0; dc < 8; ++dc) {
      float4 v0 = *(const float4*)(qrow + dc * 32 + 8 * g);
      float4 v1 = *(const float4*)(qrow + dc * 32 + 8 * g + 4);
      float f[8] = {v0.x, v0.y, v0.z, v0.w, v1.x, v1.y, v1.z, v1.w};
      f16x8 H, L;
#pragma unroll
      for (int j = 0; j < 8; ++j) {
        _Float16 h = (_Float16)f[j];
        H[j] = h;
        L[j] = (_Float16)(f[j] - (float)h);
      }
      qh[tt][dc] = H; ql[tt][dc] = L;
    }
  }

  asm volatile("s_waitcnt vmcnt(0)" ::: "memory");
  __builtin_amdgcn_sched_barrier(0);
  __builtin_amdgcn_s_barrier();
  __builtin_amdgcn_sched_barrier(0);

  float m_run[2] = {-INFINITY, -INFINITY}, l_run[2] = {0.f, 0.f};
  f32x4 ctx[2][16];
#pragma unroll
  for (int tt = 0; tt < 2; ++tt)
#pragma unroll
    for (int i = 0; i < 16; ++i) ctx[tt][i] = (f32x4){0.f, 0.f, 0.f, 0.f};

  f32x4 sA[2], sB[2];

  auto QK = [&](int slot, f32x4 oA[2], f32x4 oB[2]) {
    const char* Kb = grpK + slot * 16384;
#pragma unroll
    for (int tt = 0; tt < 2; ++tt) {
      oA[tt] = (f32x4){0.f, 0.f, 0.f, 0.f};
      oB[tt] = (f32x4){0.f, 0.f, 0.f, 0.f};
    }
#pragma unroll
    for (int dc = 0; dc < 8; ++dc) {
      int x = dc * 4 + g;
      int xsw = (x & 24) | ((x ^ c) & 7);
      f16x8 k0 = *(const f16x8*)(Kb + c * 512 + (xsw << 4));
      f16x8 k1 = *(const f16x8*)(Kb + (16 + c) * 512 + (xsw << 4));
#pragma unroll
      for (int tt = 0; tt < 2; ++tt) {
        oA[tt] = __builtin_amdgcn_mfma_f32_16x16x32_f16(k0, qh[tt][dc], oA[tt], 0, 0, 0);
        oA[tt] = __builtin_amdgcn_mfma_f32_16x16x32_f16(k0, ql[tt][dc], oA[tt], 0, 0, 0);
        oB[tt] = __builtin_amdgcn_mfma_f32_16x16x32_f16(k1, qh[tt][dc], oB[tt], 0, 0, 0);
        oB[tt] = __builtin_amdgcn_mfma_f32_16x16x32_f16(k1, ql[tt][dc], oB[tt], 0, 0, 0);
      }
    }
  };

  // QK for tile 0
  QK(0, sA, sB);

  int kslot_rd = 1, kslot_wr = 0;

  for (int it = 0; it < NIT; ++it) {
    const bool hasNext = (it + 1 < NIT);
    f32x4 nA[2], nB[2];
    if (hasNext) QK(kslot_rd, nA, nB);   // QK(it+1), interleaves with SM below

    // ---- SM(it): in-lane softmax, builds f16x4 B-fragments, no shuffles ----
    f16x4 bfA[2], bfB[2];
    {
      float vx[2];
#pragma unroll
      for (int tt = 0; tt < 2; ++tt) {
        float v = fmaxf(fmaxf(fmaxf(sA[tt][0], sA[tt][1]), fmaxf(sA[tt][2], sA[tt][3])),
                        fmaxf(fmaxf(sB[tt][0], sB[tt][1]), fmaxf(sB[tt][2], sB[tt][3])));
        v = fmaxf(v, __shfl_xor(v, 16, 64));
        v = fmaxf(v, __shfl_xor(v, 32, 64));
        vx[tt] = v;
      }
      bool need = (vx[0] > m_run[0] + 8.0f) || (vx[1] > m_run[1] + 8.0f);
      if (__any(need)) {
#pragma unroll
        for (int tt = 0; tt < 2; ++tt) {
          float mn = fmaxf(m_run[tt], vx[tt]);
          float alpha = __expf(m_run[tt] - mn);
          l_run[tt] *= alpha;
#pragma unroll
          for (int i = 0; i < 16; ++i) ctx[tt][i] *= alpha;
          m_run[tt] = mn;
        }
      }
#pragma unroll
      for (int tt = 0; tt < 2; ++tt) {
        float p0 = __expf(sA[tt][0] - m_run[tt]), p1 = __expf(sA[tt][1] - m_run[tt]);
        float p2 = __expf(sA[tt][2] - m_run[tt]), p3 = __expf(sA[tt][3] - m_run[tt]);
        float p4 = __expf(sB[tt][0] - m_run[tt]), p5 = __expf(sB[tt][1] - m_run[tt]);
        float p6 = __expf(sB[tt][2] - m_run[tt]), p7 = __expf(sB[tt][3] - m_run[tt]);
        float ps = ((p0 + p1) + (p2 + p3)) + ((p4 + p5) + (p6 + p7));
        ps += __shfl_xor(ps, 16, 64);
        ps += __shfl_xor(ps, 32, 64);
        l_run[tt] += ps;
        bfA[tt] = __builtin_bit_cast(f16x4, make_int2((int)pk2(p0, p1), (int)pk2(p2, p3)));
        bfB[tt] = __builtin_bit_cast(f16x4, make_int2((int)pk2(p4, p5), (int)pk2(p6, p7)));
      }
    }

    // ---- PV(it): 16x16x16 MFMAs, one b128 V-read feeds both e-halves & tiles ----
    {
      const char* Vb = grpV + (it & 1) * 16384;
#pragma unroll
      for (int dt = 0; dt < 16; ++dt) {
        int row = dt * 16 + c;
        f16x8 v8 = *(const f16x8*)(Vb + row * 64 + ((g ^ ((row >> 1) & 3)) << 4));
        int4 vi = __builtin_bit_cast(int4, v8);
        f16x4 a0 = __builtin_bit_cast(f16x4, make_int2(vi.x, vi.y));  // e 4g..4g+3
        f16x4 a1 = __builtin_bit_cast(f16x4, make_int2(vi.z, vi.w));  // e 16+4g..+3
        ctx[0][dt] = __builtin_amdgcn_mfma_f32_16x16x16f16(a0, bfA[0], ctx[0][dt], 0, 0, 0);
        ctx[0][dt] = __builtin_amdgcn_mfma_f32_16x16x16f16(a1, bfB[0], ctx[0][dt], 0, 0, 0);
        ctx[1][dt] = __builtin_amdgcn_mfma_f32_16x16x16f16(a0, bfA[1], ctx[1][dt], 0, 0, 0);
        ctx[1][dt] = __builtin_amdgcn_mfma_f32_16x16x16f16(a1, bfB[1], ctx[1][dt], 0, 0, 0);
      }
    }

    if (hasNext) {
#pragma unroll
      for (int tt = 0; tt < 2; ++tt) { sA[tt] = nA[tt]; sB[tt] = nB[tt]; }
    }

    // ---- sync: iteration-old loads are long-landed -> cheap vmcnt(0) ----
    asm volatile("s_waitcnt vmcnt(0) lgkmcnt(0)" ::: "memory");
    __builtin_amdgcn_sched_barrier(0);
    __builtin_amdgcn_s_barrier();
    __builtin_amdgcn_sched_barrier(0);

    if (it + 3 < NIT) KSTAGE(kslot_wr, it + 3);
    if (it + 2 < NIT) VSTAGE(it & 1, it + 2);
    __builtin_amdgcn_sched_barrier(0);

    kslot_wr = kslot_rd;
    kslot_rd = (kslot_rd >= 2) ? 0 : kslot_rd + 1;
  }

  // ---- cross-group merge (2 e-groups) ----
  __syncthreads();
  float* mlb = (float*)(lds + 65536);
  if (g == 0) {
#pragma unroll
    for (int tt = 0; tt < 2; ++tt) {
      int idx = wr * 64 + tw * 32 + tt * 16 + c;
      mlb[idx * 2 + 0] = m_run[tt];
      mlb[idx * 2 + 1] = l_run[tt];
    }
  }
  __syncthreads();
  float fme[2], invL[2];
#pragma unroll
  for (int tt = 0; tt < 2; ++tt) {
    int idx_o = (1 - wr) * 64 + tw * 32 + tt * 16 + c;
    float mo = mlb[idx_o * 2 + 0], lo = mlb[idx_o * 2 + 1];
    float M = fmaxf(m_run[tt], mo);
    fme[tt] = __expf(m_run[tt] - M);
    float L = l_run[tt] * fme[tt] + lo * __expf(mo - M);
    invL[tt] = 1.0f / L;
  }

  float* Xb = (float*)lds;   // [256 d][64 t] f32 = 64 KiB
  if (wr == 1) {
#pragma unroll
    for (int tt = 0; tt < 2; ++tt)
#pragma unroll
      for (int dt = 0; dt < 16; ++dt)
#pragma unroll
        for (int r = 0; r < 4; ++r) {
          int d = dt * 16 + 4 * g + r;
          Xb[d * 64 + tw * 32 + tt * 16 + c] = ctx[tt][dt][r] * fme[tt];
        }
  }
  __syncthreads();
  if (wr == 0) {
#pragma unroll
    for (int tt = 0; tt < 2; ++tt) {
      float* orow = outB + (size_t)(tbase + tt * 16 + c) * 512 + 256;
#pragma unroll
      for (int dt = 0; dt < 16; ++dt) {
        float vv[4];
#pragma unroll
        for (int r = 0; r < 4; ++r) {
          int d = dt * 16 + 4 * g + r;
          vv[r] = (ctx[tt][dt][r] * fme[tt] + Xb[d * 64 + tw * 32 + tt * 16 + c]) * invL[tt];
        }
        float4 v; v.x = vv[0]; v.y = vv[1]; v.z = vv[2]; v.w = vv[3];
        *(float4*)(orow + dt * 16 + 4 * g) = v;
      }
    }
  }
}

extern "C" void kernel_launch(void* const* d_in, const int* in_sizes, int n_in,
                              void* d_out, int out_size, void* d_ws, size_t ws_size,
                              hipStream_t stream) {
  const float* enc = (const float*)d_in[0];
  const float* dec = (const float*)d_in[1];
  float* out = (float*)d_out;
  (void)in_sizes; (void)n_in; (void)out_size; (void)ws_size;

  _Float16* encK  = (_Float16*)d_ws;                           // 8 MiB
  _Float16* encVt = (_Float16*)((char*)d_ws + 8388608);        // 8 MiB

  prep_fused<<<1024, 256, 0, stream>>>(enc, encK, encVt);
  luong_main<<<256, 256, 163840, stream>>>(encK, encVt, dec, out);
}